// Round 1
// baseline (907.229 us; speedup 1.0000x reference)
//
#include <hip/hip_runtime.h>
#include <math.h>

#define NTOK   32768
#define DDIM   2048
#define NEXP   64
#define TOKW   64              // tokens per workgroup (= lanes per wave)
#define NG     4               // D-split groups = waves per WG
#define DPER   (DDIM / NG)     // 512 d-values per wave
#define CHUNK  32              // d staged per round per group
#define ROUNDS (DPER / CHUNK)  // 16
#define JQ     (CHUNK / 4)     // 8 float4 per chunk

union Smem {
    // x staging: [group][d-quad][token(+pad)] ; pad 64->65 float4s breaks
    // the 8-way write conflict (stride 65*4 words ≡ 4 mod 32 banks -> 2-way, free)
    float4 xs[NG][JQ][65];
    struct { float4 A[16][TOKW]; float4 B[16][TOKW]; } red;  // partial-logit reduce
};

__global__ __launch_bounds__(256, 3)
void router_kernel(const float* __restrict__ x, const float* __restrict__ wde,
                   float* __restrict__ out) {
    __shared__ Smem sm;
    const int tid  = threadIdx.x;
    const int t    = tid & 63;   // token within tile
    const int g    = tid >> 6;   // wave = d-quarter
    const int tok0 = blockIdx.x * TOKW;

    float acc[NEXP];
    #pragma unroll
    for (int e = 0; e < NEXP; ++e) acc[e] = 0.0f;

    // staging coordinates: flat f = tid + 256*i over 64tok x 4grp x 8quads
    int s_q[8], s_tk[8], s_j[8];
    #pragma unroll
    for (int i = 0; i < 8; ++i) {
        int f = tid + 256 * i;
        s_q[i]  = f >> 9;
        int f2  = f & 511;
        s_tk[i] = f2 >> 3;
        s_j[i]  = f2 & 7;
    }

    float4 stg[8];
    auto issue = [&](int r) {
        #pragma unroll
        for (int i = 0; i < 8; ++i) {
            const float* gp = x + (size_t)(tok0 + s_tk[i]) * DDIM
                                + s_q[i] * DPER + r * CHUNK + s_j[i] * 4;
            stg[i] = *(const float4*)gp;
        }
    };

    issue(0);
    for (int r = 0; r < ROUNDS; ++r) {
        // park staged regs into LDS (prev round's compute finished at loop-end sync)
        #pragma unroll
        for (int i = 0; i < 8; ++i) sm.xs[s_q[i]][s_j[i]][s_tk[i]] = stg[i];
        __syncthreads();
        if (r + 1 < ROUNDS) issue(r + 1);   // prefetch next chunk under compute

        const int dbase = g * DPER + r * CHUNK;
        for (int j = 0; j < JQ; ++j) {
            float4 xq = sm.xs[g][j][t];     // conflict-free contiguous float4
            #pragma unroll
            for (int c = 0; c < 4; ++c) {
                float xv = (c == 0) ? xq.x : (c == 1) ? xq.y : (c == 2) ? xq.z : xq.w;
                const float* wr = wde + (size_t)(dbase + 4 * j + c) * NEXP;  // wave-uniform -> s_load
                #pragma unroll
                for (int e = 0; e < NEXP; ++e)
                    acc[e] = fmaf(xv, wr[e], acc[e]);
            }
        }
        __syncthreads();
    }

    // ---- cross-wave reduction of D-split partials (tree: g1->g0, g3->g2, g2->g0)
    if (g == 1) {
        #pragma unroll
        for (int i = 0; i < 16; ++i)
            sm.red.A[i][t] = make_float4(acc[4*i], acc[4*i+1], acc[4*i+2], acc[4*i+3]);
    }
    if (g == 3) {
        #pragma unroll
        for (int i = 0; i < 16; ++i)
            sm.red.B[i][t] = make_float4(acc[4*i], acc[4*i+1], acc[4*i+2], acc[4*i+3]);
    }
    __syncthreads();
    if (g == 0) {
        #pragma unroll
        for (int i = 0; i < 16; ++i) {
            float4 v = sm.red.A[i][t];
            acc[4*i] += v.x; acc[4*i+1] += v.y; acc[4*i+2] += v.z; acc[4*i+3] += v.w;
        }
    }
    if (g == 2) {
        #pragma unroll
        for (int i = 0; i < 16; ++i) {
            float4 v = sm.red.B[i][t];
            acc[4*i] += v.x; acc[4*i+1] += v.y; acc[4*i+2] += v.z; acc[4*i+3] += v.w;
        }
    }
    __syncthreads();
    if (g == 2) {
        #pragma unroll
        for (int i = 0; i < 16; ++i)
            sm.red.A[i][t] = make_float4(acc[4*i], acc[4*i+1], acc[4*i+2], acc[4*i+3]);
    }
    __syncthreads();

    if (g == 0) {
        #pragma unroll
        for (int i = 0; i < 16; ++i) {
            float4 v = sm.red.A[i][t];
            acc[4*i] += v.x; acc[4*i+1] += v.y; acc[4*i+2] += v.z; acc[4*i+3] += v.w;
        }

        // ---- full softmax over 64 experts (fp32, max-subtracted like jax)
        float m = acc[0];
        #pragma unroll
        for (int e = 1; e < NEXP; ++e) m = fmaxf(m, acc[e]);
        float s = 0.0f;
        #pragma unroll
        for (int e = 0; e < NEXP; ++e) { acc[e] = expf(acc[e] - m); s += acc[e]; }

        // ---- top-8 (descending; strict '>' keeps lowest index on ties, matching lax.top_k)
        unsigned long long chosen = 0ull;
        float wv[8]; float wi[8];
        #pragma unroll
        for (int k = 0; k < 8; ++k) {
            float best = -1.0f; int bi = 0;
            #pragma unroll
            for (int e = 0; e < NEXP; ++e) {
                bool ok = (((chosen >> e) & 1ull) == 0ull) && (acc[e] > best);
                best = ok ? acc[e] : best;
                bi   = ok ? e : bi;
            }
            chosen |= (1ull << bi);
            wv[k] = best;
            wi[k] = (float)bi;
        }

        // ---- second softmax over the 8 selected gating probabilities
        float p0 = wv[0] / s;            // wv sorted descending -> p0 is max
        float e2[8]; float s2 = 0.0f;
        #pragma unroll
        for (int k = 0; k < 8; ++k) { e2[k] = expf(wv[k] / s - p0); s2 += e2[k]; }

        const int tok = tok0 + t;
        float4* ow = (float4*)(out + (size_t)tok * 8);
        ow[0] = make_float4(e2[0]/s2, e2[1]/s2, e2[2]/s2, e2[3]/s2);
        ow[1] = make_float4(e2[4]/s2, e2[5]/s2, e2[6]/s2, e2[7]/s2);
        // indices written as float values (harness reads whole d_out as fp32)
        float4* oi = (float4*)(out + (size_t)NTOK * 8 + (size_t)tok * 8);
        oi[0] = make_float4(wi[0], wi[1], wi[2], wi[3]);
        oi[1] = make_float4(wi[4], wi[5], wi[6], wi[7]);
    }
}

extern "C" void kernel_launch(void* const* d_in, const int* in_sizes, int n_in,
                              void* d_out, int out_size, void* d_ws, size_t ws_size,
                              hipStream_t stream) {
    const float* x   = (const float*)d_in[0];
    const float* wde = (const float*)d_in[1];
    float* out       = (float*)d_out;
    dim3 grid(NTOK / TOKW);   // 512 workgroups
    dim3 block(256);
    router_kernel<<<grid, block, 0, stream>>>(x, wde, out);
}

// Round 3
// 572.097 us; speedup vs baseline: 1.5858x; 1.5858x over previous
//
#include <hip/hip_runtime.h>
#include <math.h>

#define NTOK   32768
#define DDIM   2048
#define NEXP   64
#define TOKW   64              // tokens per workgroup
#define BLOCK  512             // 8 waves
#define EPW    8               // experts per wave (8 waves x 8 = 64)
#define DCH    64              // d-values staged per round
#define ROUNDS (DDIM / DCH)    // 32
#define RPQ    (ROUNDS / 4)    // 8 rounds per 512-d quarter
#define JQ     (DCH / 4)       // 16 float4 per token per round
#define ROWQ   (JQ + 1)        // padded LDS row stride (17 float4) -> conflict-free

union Smem {
    float4 xs[2][TOKW][ROWQ];        // 34816 B, double-buffered x staging
    float  logit[TOKW][NEXP + 1];    // 16640 B, reused after main loop
};

__global__ __launch_bounds__(BLOCK, 4)
void router_kernel(const float* __restrict__ x, const float* __restrict__ wde,
                   float* __restrict__ out) {
    __shared__ Smem sm;
    const int tid = threadIdx.x;
    const int t   = tid & 63;                                        // token lane
    const int eb  = __builtin_amdgcn_readfirstlane((tid >> 6) * EPW); // wave's expert base
    const int tok0 = blockIdx.x * TOKW;
    const float* __restrict__ wslice = wde + eb;

    // 4 accumulators per expert: one per contiguous 512-d quarter.
    // This reproduces R1's accumulation order BITWISE (sequential fmaf within
    // each quarter, pairwise (q0+q1)+(q2+q3) combine) -> identical logits ->
    // identical top-k indices vs the reference (R1 passed with 0 index flips).
    float accq[4][EPW];
    #pragma unroll
    for (int q = 0; q < 4; ++q)
        #pragma unroll
        for (int k = 0; k < EPW; ++k) accq[q][k] = 0.0f;

    // staging coords: flat = tid + BLOCK*i over 64 tok x 16 float4
    int s_tok[2], s_j[2];
    #pragma unroll
    for (int i = 0; i < 2; ++i) {
        int f = tid + BLOCK * i;
        s_tok[i] = f >> 4;
        s_j[i]   = f & 15;
    }

    float4 stg[2];
    auto issue = [&](int r) {
        #pragma unroll
        for (int i = 0; i < 2; ++i) {
            const float* gp = x + (size_t)(tok0 + s_tok[i]) * DDIM + r * DCH + s_j[i] * 4;
            stg[i] = *(const float4*)gp;
        }
    };

    issue(0);
    #pragma unroll
    for (int q = 0; q < 4; ++q) {            // fully unrolled: accq[q] stays in regs
        for (int rr = 0; rr < RPQ; ++rr) {
            const int r = q * RPQ + rr;
            #pragma unroll
            for (int i = 0; i < 2; ++i) sm.xs[r & 1][s_tok[i]][s_j[i]] = stg[i];
            __syncthreads();                  // single barrier/round; 2 buffers make it safe
            if (r + 1 < ROUNDS) issue(r + 1); // prefetch next chunk under compute

            const int dbase = r * DCH;
            #pragma unroll 4
            for (int j = 0; j < JQ; ++j) {
                float4 xq = sm.xs[r & 1][t][j];   // padded rows: conflict-free b128
                #pragma unroll
                for (int c = 0; c < 4; ++c) {
                    float xv = (c == 0) ? xq.x : (c == 1) ? xq.y : (c == 2) ? xq.z : xq.w;
                    const float* wr = wslice + (size_t)(dbase + 4 * j + c) * NEXP; // uniform -> s_load
                    #pragma unroll
                    for (int k = 0; k < EPW; ++k)
                        accq[q][k] = fmaf(xv, wr[k], accq[q][k]);
                }
            }
        }
    }
    __syncthreads();

    // combine quarters exactly like R1's tree: (q0+q1)+(q2+q3)
    float acc[EPW];
    #pragma unroll
    for (int k = 0; k < EPW; ++k) {
        float a01 = accq[0][k] + accq[1][k];
        float a23 = accq[2][k] + accq[3][k];
        acc[k] = a01 + a23;
    }

    // each wave deposits its 8 logits per token; stride 65 -> conflict-free
    #pragma unroll
    for (int k = 0; k < EPW; ++k) sm.logit[t][eb + k] = acc[k];
    __syncthreads();

    if (tid < 64) {
        const int tok = tok0 + tid;
        float lg[NEXP];
        #pragma unroll
        for (int e = 0; e < NEXP; ++e) lg[e] = sm.logit[tid][e];

        // softmax over 64 experts (fp32, max-subtracted)
        float m = lg[0];
        #pragma unroll
        for (int e = 1; e < NEXP; ++e) m = fmaxf(m, lg[e]);
        float s = 0.0f;
        #pragma unroll
        for (int e = 0; e < NEXP; ++e) { lg[e] = expf(lg[e] - m); s += lg[e]; }

        // top-8, strict '>' keeps lowest index on ties (lax.top_k semantics)
        unsigned long long chosen = 0ull;
        float wv[8], wi[8];
        #pragma unroll
        for (int k = 0; k < 8; ++k) {
            float best = -1.0f; int bi = 0;
            #pragma unroll
            for (int e = 0; e < NEXP; ++e) {
                bool ok = (((chosen >> e) & 1ull) == 0ull) && (lg[e] > best);
                best = ok ? lg[e] : best;
                bi   = ok ? e : bi;
            }
            chosen |= (1ull << bi);
            wv[k] = best;
            wi[k] = (float)bi;
        }

        // second softmax over the 8 selected gating probabilities
        float p0 = wv[0] / s;
        float e2[8]; float s2 = 0.0f;
        #pragma unroll
        for (int k = 0; k < 8; ++k) { e2[k] = expf(wv[k] / s - p0); s2 += e2[k]; }

        float4* ow = (float4*)(out + (size_t)tok * 8);
        ow[0] = make_float4(e2[0]/s2, e2[1]/s2, e2[2]/s2, e2[3]/s2);
        ow[1] = make_float4(e2[4]/s2, e2[5]/s2, e2[6]/s2, e2[7]/s2);
        float4* oi = (float4*)(out + (size_t)NTOK * 8 + (size_t)tok * 8);
        oi[0] = make_float4(wi[0], wi[1], wi[2], wi[3]);
        oi[1] = make_float4(wi[4], wi[5], wi[6], wi[7]);
    }
}

extern "C" void kernel_launch(void* const* d_in, const int* in_sizes, int n_in,
                              void* d_out, int out_size, void* d_ws, size_t ws_size,
                              hipStream_t stream) {
    const float* x   = (const float*)d_in[0];
    const float* wde = (const float*)d_in[1];
    float* out       = (float*)d_out;
    router_kernel<<<dim3(NTOK / TOKW), dim3(BLOCK), 0, stream>>>(x, wde, out);
}

// Round 4
// 526.745 us; speedup vs baseline: 1.7223x; 1.0861x over previous
//
#include <hip/hip_runtime.h>
#include <math.h>

#define NTOK   32768
#define DDIM   2048
#define NEXP   64
#define TOKB   64              // tokens per block
#define BLOCK  512             // 8 waves
#define NT     8               // tokens per wave
#define DCH    64              // d-values per round
#define ROUNDS (DDIM / DCH)    // 32
#define RPQ    (ROUNDS / 4)    // 8 rounds per 512-d quarter

union Smem {
    struct {
        float4 xs[2][TOKB][DCH / 4];   // 32 KB: x chunk, double-buffered
        float4 ws[2][DCH][NEXP / 4];   // 32 KB: W chunk, double-buffered
    } st;
    float logit[TOKB][NEXP + 1];       // epilogue gather (stride 65, conflict-free)
};

__global__ __launch_bounds__(BLOCK, 4)
void router_kernel(const float* __restrict__ x, const float* __restrict__ wde,
                   float* __restrict__ out) {
    __shared__ Smem sm;
    const int tid   = threadIdx.x;
    const int lane  = tid & 63;        // lane = expert index
    const int w     = tid >> 6;        // wave id
    const int wtok0 = w * NT;          // wave's first local token
    const int tok0  = blockIdx.x * TOKB;

    // accq[q][i]: logit partial for (token wtok0+i, expert lane), quarter q.
    // Sequential fmaf over ascending d within quarter, combined (q0+q1)+(q2+q3):
    // bitwise-identical to R3's validated accumulation order.
    float accq[4][NT];
    #pragma unroll
    for (int q = 0; q < 4; ++q)
        #pragma unroll
        for (int i = 0; i < NT; ++i) accq[q][i] = 0.0f;

    // staging: 1024 float4 of x + 1024 float4 of W per round, 2+2 per thread
    int s_row[2], s_j[2];
    #pragma unroll
    for (int i = 0; i < 2; ++i) {
        int f = tid + BLOCK * i;
        s_row[i] = f >> 4;             // token (x) or d (W)
        s_j[i]   = f & 15;             // float4 column
    }

    float4 sx[2], sw[2];
    auto issue = [&](int r) {
        #pragma unroll
        for (int i = 0; i < 2; ++i) {
            sx[i] = *(const float4*)(x + (size_t)(tok0 + s_row[i]) * DDIM + r * DCH + s_j[i] * 4);
            sw[i] = *(const float4*)(wde + (size_t)(r * DCH + s_row[i]) * NEXP + s_j[i] * 4);
        }
    };

    issue(0);
    #pragma unroll
    for (int q = 0; q < 4; ++q) {              // unrolled: accq[q] stays in registers
        for (int rr = 0; rr < RPQ; ++rr) {
            const int r = q * RPQ + rr;
            const int b = r & 1;
            #pragma unroll
            for (int i = 0; i < 2; ++i) {
                sm.st.xs[b][s_row[i]][s_j[i]] = sx[i];
                sm.st.ws[b][s_row[i]][s_j[i]] = sw[i];
            }
            __syncthreads();                   // dbuf makes 1 barrier/round safe
            if (r + 1 < ROUNDS) issue(r + 1);  // global prefetch under compute

            const float* __restrict__ wrow = (const float*)sm.st.ws[b]; // [DCH][64]
            const float* __restrict__ xrow = (const float*)sm.st.xs[b]; // [TOKB][64]

            #pragma unroll 4
            for (int j4 = 0; j4 < DCH / 4; ++j4) {
                // W[d][lane] for 4 consecutive d: conflict-free b32 (2-way only)
                float w0 = wrow[(4 * j4 + 0) * NEXP + lane];
                float w1 = wrow[(4 * j4 + 1) * NEXP + lane];
                float w2 = wrow[(4 * j4 + 2) * NEXP + lane];
                float w3 = wrow[(4 * j4 + 3) * NEXP + lane];
                #pragma unroll
                for (int i = 0; i < NT; ++i) {
                    // all lanes same address -> LDS broadcast, no conflict
                    float4 xq = *(const float4*)(xrow + (wtok0 + i) * DCH + 4 * j4);
                    accq[q][i] = fmaf(xq.x, w0, accq[q][i]);
                    accq[q][i] = fmaf(xq.y, w1, accq[q][i]);
                    accq[q][i] = fmaf(xq.z, w2, accq[q][i]);
                    accq[q][i] = fmaf(xq.w, w3, accq[q][i]);
                }
            }
        }
    }
    __syncthreads();   // all reads of st done before union reuse

    // combine quarters exactly like R3: (q0+q1)+(q2+q3)
    #pragma unroll
    for (int i = 0; i < NT; ++i) {
        float a01 = accq[0][i] + accq[1][i];
        float a23 = accq[2][i] + accq[3][i];
        sm.logit[wtok0 + i][lane] = a01 + a23;   // consecutive lanes -> conflict-free
    }
    __syncthreads();

    if (tid < 64) {
        const int tok = tok0 + tid;
        float lg[NEXP];
        #pragma unroll
        for (int e = 0; e < NEXP; ++e) lg[e] = sm.logit[tid][e];

        // softmax over 64 experts (fp32, max-subtracted)
        float m = lg[0];
        #pragma unroll
        for (int e = 1; e < NEXP; ++e) m = fmaxf(m, lg[e]);
        float s = 0.0f;
        #pragma unroll
        for (int e = 0; e < NEXP; ++e) { lg[e] = expf(lg[e] - m); s += lg[e]; }

        // top-8, strict '>' keeps lowest index on ties (lax.top_k semantics)
        unsigned long long chosen = 0ull;
        float wv[8], wi[8];
        #pragma unroll
        for (int k = 0; k < 8; ++k) {
            float best = -1.0f; int bi = 0;
            #pragma unroll
            for (int e = 0; e < NEXP; ++e) {
                bool ok = (((chosen >> e) & 1ull) == 0ull) && (lg[e] > best);
                best = ok ? lg[e] : best;
                bi   = ok ? e : bi;
            }
            chosen |= (1ull << bi);
            wv[k] = best;
            wi[k] = (float)bi;
        }

        // second softmax over the 8 selected gating probabilities
        float p0 = wv[0] / s;
        float e2[8]; float s2 = 0.0f;
        #pragma unroll
        for (int k = 0; k < 8; ++k) { e2[k] = expf(wv[k] / s - p0); s2 += e2[k]; }

        float4* ow = (float4*)(out + (size_t)tok * 8);
        ow[0] = make_float4(e2[0]/s2, e2[1]/s2, e2[2]/s2, e2[3]/s2);
        ow[1] = make_float4(e2[4]/s2, e2[5]/s2, e2[6]/s2, e2[7]/s2);
        float4* oi = (float4*)(out + (size_t)NTOK * 8 + (size_t)tok * 8);
        oi[0] = make_float4(wi[0], wi[1], wi[2], wi[3]);
        oi[1] = make_float4(wi[4], wi[5], wi[6], wi[7]);
    }
}

extern "C" void kernel_launch(void* const* d_in, const int* in_sizes, int n_in,
                              void* d_out, int out_size, void* d_ws, size_t ws_size,
                              hipStream_t stream) {
    const float* x   = (const float*)d_in[0];
    const float* wde = (const float*)d_in[1];
    float* out       = (float*)d_out;
    router_kernel<<<dim3(NTOK / TOKB), dim3(BLOCK), 0, stream>>>(x, wde, out);
}